// Round 7
// baseline (257.172 us; speedup 1.0000x reference)
//
#include <hip/hip_runtime.h>
#include <stdint.h>
#include <math.h>

typedef __attribute__((ext_vector_type(8))) __bf16 bf16x8;
typedef __attribute__((ext_vector_type(4))) __bf16 bf16x4;
typedef __attribute__((ext_vector_type(4))) float f32x4;
typedef __attribute__((ext_vector_type(16))) float f32x16;

#define MFMA16(A, B, C) __builtin_amdgcn_mfma_f32_16x16x32_bf16((A), (B), (C), 0, 0, 0)
#define MFMA32(A, B, C) __builtin_amdgcn_mfma_f32_32x32x16_bf16((A), (B), (C), 0, 0, 0)

#if defined(__has_builtin)
#if __has_builtin(__builtin_amdgcn_exp2f)
#define EXP2(x) __builtin_amdgcn_exp2f(x)
#else
#define EXP2(x) exp2f(x)
#endif
#else
#define EXP2(x) exp2f(x)
#endif

static constexpr int kT  = 2048;
static constexpr int kC  = 1024;
static constexpr int kHD = 64;
// q pre-scale: (1/sqrt(64)) * log2(e) so exp2(s') == exp(q.k/8)
#define QSCALE 0.1803368801111204f

__device__ __forceinline__ void g2l16(const void* g, void* l) {
  __builtin_amdgcn_global_load_lds(
      (const __attribute__((address_space(1))) uint32_t*)g,
      (__attribute__((address_space(3))) uint32_t*)l, 16, 0, 0);
}

// ---------------- x (f32) -> bf16, row-major [M, C] ----------------
__global__ __launch_bounds__(256) void k_convert_x(const float* __restrict__ x,
                                                   __bf16* __restrict__ xb) {
  int i = (blockIdx.x * 256 + threadIdx.x) * 4;
  f32x4 v = *(const f32x4*)(x + i);
  bf16x4 o;
  o[0] = (__bf16)v[0]; o[1] = (__bf16)v[1]; o[2] = (__bf16)v[2]; o[3] = (__bf16)v[3];
  *(bf16x4*)(xb + i) = o;
}

// ---- W [K=1024, N] f32 -> W^T [N, 1024] bf16 (B^T form for GEMM) ----
__global__ __launch_bounds__(256) void k_transpose_w(const float* __restrict__ src,
                                                     __bf16* __restrict__ dst, int N) {
  __shared__ float t[32][33];
  int k0 = blockIdx.x * 32, n0 = blockIdx.y * 32;
  int c = threadIdx.x & 31, r = threadIdx.x >> 5;
#pragma unroll
  for (int i = 0; i < 4; ++i)
    t[r + i * 8][c] = src[(size_t)(k0 + r + i * 8) * N + n0 + c];
  __syncthreads();
#pragma unroll
  for (int i = 0; i < 4; ++i)
    dst[(size_t)(n0 + r + i * 8) * 1024 + k0 + c] = (__bf16)t[c][r + i * 8];
}

static constexpr int GK = 1024;
static constexpr int GNT = GK / 32;   // 32 K-tiles

// ---------------- QKV GEMM: BM=256, BN=128, 128x64 per wave -------------
// Round-7 retile: the 64x64/wave tiling was LDS-BW-capped (32 FLOP per
// LDS-byte -> 385 LDS-cy vs 258 MFMA-cy per CU-iter). 128x64/wave (acc[8][4])
// gives 42.7 FLOP/B and 32 MFMA per barrier. Same ring-3 counted-vmcnt
// skeleton + granule-XOR swizzle as r6 (PMC-verified 0 conflicts); 6 g2l16
// per thread per iter -> vmcnt(6). LDS 72 KB -> 2 blocks/CU; grid 768 = 3
// blocks/CU balanced. Outputs: q (scaled), k [B,H,T,hd]; v TRANSPOSED
// [bh][d][t'] with t' bits 2<->3 swapped in 16-groups (flash PV identity).
__global__ __launch_bounds__(256, 2) void k_gemm_qkv(const __bf16* __restrict__ A,
                                                     const __bf16* __restrict__ Bw,
                                                     const float* __restrict__ bias,
                                                     __bf16* __restrict__ qo,
                                                     __bf16* __restrict__ ko,
                                                     __bf16* __restrict__ vo) {
  __shared__ __bf16 As[3][256 * 32];   // 3 x 16 KiB
  __shared__ __bf16 Bs[3][128 * 32];   // 3 x 8 KiB

  const int tid = threadIdx.x;
  const int wave = tid >> 6, lane = tid & 63;
  const int lo = lane & 15, hi = lane >> 4;
  const int wr = wave & 1, wc = wave >> 1;

  // XCD-bijective chunking (768 % 8 == 0), bn-major: each XCD holds 4
  // A-panels (2 MB, L2-resident) and streams B (L3-resident).
  const int id = (int)blockIdx.x;
  const int wg = (id & 7) * 96 + (id >> 3);
  const int bm = wg / 24, bn = wg % 24;
  const int m0 = bm * 256, n0 = bn * 128;

  // staging: A granules G = tid + p*256 (p=0..3), B granules G = tid + p*256
  // (p=0..1). r = G>>2, c = G&3 = tid&3; swizzle gs = c ^ ((r>>1)&3) is
  // p-invariant (64p>>1 ≡ 0 mod 4). Linear LDS dest (tid + 256p)*8.
  const int rA = tid >> 2, cG = tid & 3;
  const int gs = cG ^ ((rA >> 1) & 3);
  const __bf16* ga = A + (size_t)(m0 + rA) * GK + gs * 8;
  const __bf16* gb = Bw + (size_t)(n0 + rA) * GK + gs * 8;

  // fragment read offsets: row = base16 + lo -> (row>>1)&3 == (lo>>1)&3
  const int fsw = (hi ^ ((lo >> 1) & 3)) * 8;
  const int offA = (wr * 128 + lo) * 32 + fsw;   // + m*16*32 per m-frag
  const int offB = (wc * 64 + lo) * 32 + fsw;    // + n*16*32 per n-frag

  f32x4 acc[8][4] = {};

#define QSTAGE(jt, bufi)                                                     \
  {                                                                          \
    g2l16(ga + (jt) * 32,                       &As[(bufi)][tid * 8]);       \
    g2l16(ga + (jt) * 32 + (size_t)64 * GK,     &As[(bufi)][2048 + tid * 8]);\
    g2l16(ga + (jt) * 32 + (size_t)128 * GK,    &As[(bufi)][4096 + tid * 8]);\
    g2l16(ga + (jt) * 32 + (size_t)192 * GK,    &As[(bufi)][6144 + tid * 8]);\
    g2l16(gb + (jt) * 32,                       &Bs[(bufi)][tid * 8]);       \
    g2l16(gb + (jt) * 32 + (size_t)64 * GK,     &Bs[(bufi)][2048 + tid * 8]);\
  }

  QSTAGE(0, 0);
  QSTAGE(1, 1);
  asm volatile("s_waitcnt vmcnt(6)" ::: "memory");
  __builtin_amdgcn_s_barrier();
  __builtin_amdgcn_sched_barrier(0);

  int rb = 0, rs = 2;
  for (int j = 0; j < GNT; ++j) {
    const __bf16* Ab = &As[rb][0];
    const __bf16* Bb = &Bs[rb][0];
    if (j < GNT - 2) QSTAGE(j + 2, rs);
    bf16x8 af[8], bfr[4];
#pragma unroll
    for (int m = 0; m < 8; ++m) af[m] = *(const bf16x8*)&Ab[offA + m * 512];
#pragma unroll
    for (int n = 0; n < 4; ++n) bfr[n] = *(const bf16x8*)&Bb[offB + n * 512];
    __builtin_amdgcn_s_setprio(1);
#pragma unroll
    for (int m = 0; m < 8; ++m)
#pragma unroll
      for (int n = 0; n < 4; ++n)
        acc[m][n] = MFMA16(af[m], bfr[n], acc[m][n]);
    __builtin_amdgcn_s_setprio(0);
    if (j < GNT - 2) {
      asm volatile("s_waitcnt vmcnt(6)" ::: "memory");
    } else if (j == GNT - 2) {
      asm volatile("s_waitcnt vmcnt(0)" ::: "memory");
    }
    if (j < GNT - 1) {
      __builtin_amdgcn_s_barrier();
      __builtin_amdgcn_sched_barrier(0);
    }
    rb = (rb == 2) ? 0 : rb + 1;
    rs = (rs == 2) ? 0 : rs + 1;
  }
#undef QSTAGE

#pragma unroll
  for (int nj = 0; nj < 4; ++nj) {
    int gn = n0 + wc * 64 + nj * 16 + lo;
    float bv = bias[gn];
    int which = gn >> 10;          // 0=q 1=k 2=v (uniform per block: 128|1024)
    int c = gn & 1023;
    int hh = c >> 6, d = c & 63;
#pragma unroll
    for (int mi = 0; mi < 8; ++mi) {
      int gm = m0 + wr * 128 + mi * 16 + hi * 4;
      int bb = gm >> 11, t0 = gm & 2047;
      if (which == 2) {
        int t0p = t0 ^ ((((t0 >> 2) ^ (t0 >> 3)) & 1) * 12);
        bf16x4 vv;
#pragma unroll
        for (int r = 0; r < 4; ++r) vv[r] = (__bf16)(acc[mi][nj][r] + bv);
        *(bf16x4*)(vo + ((size_t)(bb * 16 + hh) * 64 + d) * 2048 + t0p) = vv;
      } else {
#pragma unroll
        for (int r = 0; r < 4; ++r) {
          float val = acc[mi][nj][r] + bv;
          size_t idx = (((size_t)(bb * 16 + hh)) * 2048 + (t0 + r)) * 64 + d;
          if (which == 0)
            qo[idx] = (__bf16)(val * QSCALE);
          else
            ko[idx] = (__bf16)val;
        }
      }
    }
  }
}

// ---------------- proj GEMM: 128x128, ring-3 (r6-proven form) ------------
__global__ __launch_bounds__(256, 3) void k_gemm_proj(const __bf16* __restrict__ A,
                                                      const __bf16* __restrict__ Bw,
                                                      const float* __restrict__ bias,
                                                      float* __restrict__ out) {
  __shared__ __bf16 As[3][128 * 32];
  __shared__ __bf16 Bs[3][128 * 32];

  const int tid = threadIdx.x;
  const int wave = tid >> 6, lane = tid & 63;
  const int lo = lane & 15, hi = lane >> 4;
  const int wr = wave & 1, wc = wave >> 1;

  const int id = (int)blockIdx.x;
  const int wg = (id & 7) * 64 + (id >> 3);   // nwg = 512
  const int bm = wg / 8, bn = wg % 8;
  const int m0 = bm * 128, n0 = bn * 128;

  const int rG0 = tid >> 2, gG0 = (tid & 3) ^ ((rG0 >> 1) & 3);
  const int rG1 = (tid + 256) >> 2, gG1 = ((tid + 256) & 3) ^ ((rG1 >> 1) & 3);
  const __bf16* gaA0 = A + (size_t)(m0 + rG0) * GK + gG0 * 8;
  const __bf16* gaA1 = A + (size_t)(m0 + rG1) * GK + gG1 * 8;
  const __bf16* gbB0 = Bw + (size_t)(n0 + rG0) * GK + gG0 * 8;
  const __bf16* gbB1 = Bw + (size_t)(n0 + rG1) * GK + gG1 * 8;

  const int fsw = (hi ^ ((lo >> 1) & 3)) * 8;
  const int offA = (wr * 64 + lo) * 32 + fsw;
  const int offB = (wc * 64 + lo) * 32 + fsw;

  f32x4 acc[4][4] = {};

#define PSTAGE(jt, bufi)                                  \
  {                                                       \
    g2l16(gaA0 + (jt) * 32, &As[(bufi)][tid * 8]);        \
    g2l16(gaA1 + (jt) * 32, &As[(bufi)][2048 + tid * 8]); \
    g2l16(gbB0 + (jt) * 32, &Bs[(bufi)][tid * 8]);        \
    g2l16(gbB1 + (jt) * 32, &Bs[(bufi)][2048 + tid * 8]); \
  }

  PSTAGE(0, 0);
  PSTAGE(1, 1);
  asm volatile("s_waitcnt vmcnt(4)" ::: "memory");
  __builtin_amdgcn_s_barrier();
  __builtin_amdgcn_sched_barrier(0);

  int rb = 0, rs = 2;
  for (int j = 0; j < GNT; ++j) {
    const __bf16* Ab = &As[rb][0];
    const __bf16* Bb = &Bs[rb][0];
    if (j < GNT - 2) PSTAGE(j + 2, rs);
    bf16x8 af[4], bfr[4];
#pragma unroll
    for (int m = 0; m < 4; ++m) af[m] = *(const bf16x8*)&Ab[offA + m * 512];
#pragma unroll
    for (int n = 0; n < 4; ++n) bfr[n] = *(const bf16x8*)&Bb[offB + n * 512];
    __builtin_amdgcn_s_setprio(1);
#pragma unroll
    for (int m = 0; m < 4; ++m)
#pragma unroll
      for (int n = 0; n < 4; ++n)
        acc[m][n] = MFMA16(af[m], bfr[n], acc[m][n]);
    __builtin_amdgcn_s_setprio(0);
    if (j < GNT - 2) {
      asm volatile("s_waitcnt vmcnt(4)" ::: "memory");
    } else if (j == GNT - 2) {
      asm volatile("s_waitcnt vmcnt(0)" ::: "memory");
    }
    if (j < GNT - 1) {
      __builtin_amdgcn_s_barrier();
      __builtin_amdgcn_sched_barrier(0);
    }
    rb = (rb == 2) ? 0 : rb + 1;
    rs = (rs == 2) ? 0 : rs + 1;
  }
#undef PSTAGE

#pragma unroll
  for (int nj = 0; nj < 4; ++nj) {
    int gn = n0 + wc * 64 + nj * 16 + lo;
    float bv = bias[gn];
#pragma unroll
    for (int mi = 0; mi < 4; ++mi) {
      int gm = m0 + wr * 64 + mi * 16 + hi * 4;
#pragma unroll
      for (int r = 0; r < 4; ++r)
        out[(size_t)(gm + r) * 1024 + gn] = acc[mi][nj][r] + bv;
    }
  }
}

// ---------------- Flash attention (causal, no-max softmax) ----------------
// (r6-verified structure.) 32x32x16 swapped QK^T; lane-local linear P via
// V time-permutation; C-layout-aware normalizer redistribution.
// NEW r7: xs remap {0,1,2,3,7,6,5,4} so co-resident block pairs (id, id+256)
// have xs and 7-xs -> per-CU iteration sum constant at 50 (was 56..44).
__global__ __launch_bounds__(256, 2) void k_flash(const __bf16* __restrict__ qb,
                                                  const __bf16* __restrict__ kb,
                                                  const __bf16* __restrict__ vt,
                                                  __bf16* __restrict__ ob) {
  __shared__ __bf16 Ks[2][64 * 64];
  __shared__ __bf16 Vs[2][64 * 64];

  const int id = (int)blockIdx.x;
  const int xcd = id & 7, jj = id >> 3;
  const int bh = (jj & 7) * 8 + xcd;   // head-group pinned to one XCD
  const int xsi = jj >> 3;             // raw strip pair id, 0..7
  const int xs = (xsi < 4) ? xsi : 11 - xsi;   // tail-flattening remap
  const int b = bh >> 4, h = bh & 15;
  const int tid = threadIdx.x, wave = tid >> 6, lane = tid & 63;
  const int l31 = lane & 31, hi32 = lane >> 5;
  const int gx = l31 & 7;              // row part of granule swizzle

  // rg 0 = high strip (always active), rg 1 = low strip (active it<=2xs+1)
  const int qrow[2] = { (15 - xs) * 128 + wave * 32, xs * 128 + wave * 32 };

  // Q as B-frag: qf[rg][ks] = Q[qrow+l31][ks*16 + hi32*8 + e]
  bf16x8 qf[2][4];
#pragma unroll
  for (int rg = 0; rg < 2; ++rg) {
    const __bf16* Qp = qb + ((size_t)bh * kT + qrow[rg] + l31) * kHD + hi32 * 8;
#pragma unroll
    for (int ks = 0; ks < 4; ++ks)
      qf[rg][ks] = *(const bf16x8*)(Qp + ks * 16);
  }

  f32x16 acc[2][2] = {};      // [rg][db]: O[q=crow(reg,hi32)][d=db*32+l31]
  float srow[2] = {0.0f, 0.0f};

  const __bf16* Kbase = kb + (size_t)bh * kT * kHD;
  const __bf16* Vbase = vt + (size_t)bh * kHD * kT;

  int srcK[2], srcV[2];
#pragma unroll
  for (int p = 0; p < 2; ++p) {
    int g = wave * 64 + lane + p * 256;
    int r = g >> 3, c = g & 7;
    int cs = c ^ (r & 7);
    srcK[p] = r * kHD + cs * 8;   // + kt*64 per iteration
    srcV[p] = r * kT + cs * 8;    // + kt per iteration
  }

  const int nt = 32 - 2 * xs;

#pragma unroll
  for (int p = 0; p < 2; ++p) {
    g2l16(Kbase + srcK[p], &Ks[0][wave * 512 + p * 2048]);
    g2l16(Vbase + srcV[p], &Vs[0][wave * 512 + p * 2048]);
  }

  for (int it = 0; it < nt; ++it) {
    const int kt = it * 64;
    const int pb = it & 1;
    const bool both = (it <= 2 * xs + 1);

    __syncthreads();   // drains tile-it loads; all waves done with buf 1-pb

    if (it + 1 < nt) {
      const int kn = kt + 64;
#pragma unroll
      for (int p = 0; p < 2; ++p) {
        g2l16(Kbase + kn * kHD + srcK[p], &Ks[1 - pb][wave * 512 + p * 2048]);
        g2l16(Vbase + kn + srcV[p],       &Vs[1 - pb][wave * 512 + p * 2048]);
      }
    }

    const __bf16* Kt = &Ks[pb][0];
    const __bf16* Vt = &Vs[pb][0];

    bf16x8 pa[2][4];   // P A-frags per rg, per 16-key group

#pragma unroll
    for (int kb2 = 0; kb2 < 2; ++kb2) {
      bf16x8 ka[4];
#pragma unroll
      for (int ks = 0; ks < 4; ++ks)
        ka[ks] = *(const bf16x8*)&Kt[(kb2 * 32 + l31) * 64 +
                                     (((ks * 2 + hi32) ^ gx) * 8)];
#pragma unroll
      for (int rg = 0; rg < 2; ++rg) {
        if (rg == 1 && !both) break;
        // S^T[key][q]: lane q=l31; reg i -> key kt+kb2*32+(i&3)+8*(i>>2)+4*hi32
        f32x16 s = {};
        __builtin_amdgcn_s_setprio(1);
#pragma unroll
        for (int ks = 0; ks < 4; ++ks) s = MFMA32(ka[ks], qf[rg][ks], s);
        __builtin_amdgcn_s_setprio(0);
        const int qg = qrow[rg] + l31;
        const int kbs = kt + kb2 * 32 + 4 * hi32;
        if (kt + kb2 * 32 + 31 > qrow[rg]) {
#pragma unroll
          for (int i = 0; i < 16; ++i)
            if (kbs + (i & 3) + 8 * (i >> 2) > qg) s[i] = -INFINITY;
        }
#pragma unroll
        for (int i = 0; i < 16; ++i) s[i] = EXP2(s[i]);
        float sm = 0.0f;
#pragma unroll
        for (int i = 0; i < 16; ++i) sm += s[i];
        srow[rg] += sm;
        // P -> A-frag: LANE-LOCAL LINEAR pack (V time-permutation absorbs
        // the C-layout interleave): pa[kb2*2+a][e] = s[8a+e].
#pragma unroll
        for (int a = 0; a < 2; ++a) {
          bf16x8 p;
#pragma unroll
          for (int e = 0; e < 8; ++e) p[e] = (__bf16)s[8 * a + e];
          pa[rg][kb2 * 2 + a] = p;
        }
      }
    }

    // ---- O += P V: A=pa (P[32q x 16key]), B = V^T rows (V[key'][d]) ----
    __builtin_amdgcn_s_setprio(1);
#pragma unroll
    for (int db = 0; db < 2; ++db) {
#pragma unroll
      for (int ks = 0; ks < 4; ++ks) {
        bf16x8 vb = *(const bf16x8*)&Vt[(db * 32 + l31) * 64 +
                                        (((ks * 2 + hi32) ^ gx) * 8)];
        acc[0][db] = MFMA32(pa[0][ks], vb, acc[0][db]);
        if (both) acc[1][db] = MFMA32(pa[1][ks], vb, acc[1][db]);
      }
    }
    __builtin_amdgcn_s_setprio(0);
  }

  // epilogue: full row-sum for q=l31 via partner-half add; redistribute the
  // reciprocal to the lanes that STORE row q (C-layout row ownership).
#pragma unroll
  for (int rg = 0; rg < 2; ++rg) {
    float tot = srow[rg] + __shfl_xor(srow[rg], 32, 64);
    float invt = 1.0f / tot;       // valid for q = l31 (both hi32 halves)
    __bf16* Op = ob + ((size_t)b * kT + qrow[rg]) * kC + h * kHD;
#pragma unroll
    for (int i = 0; i < 16; ++i) {
      int q = (i & 3) + 8 * (i >> 2) + 4 * hi32;   // row this reg stores
      float inv = __shfl(invt, q, 64);             // row q's sum lives in lane q
      Op[(size_t)q * kC + l31]      = (__bf16)(acc[rg][0][i] * inv);
      Op[(size_t)q * kC + 32 + l31] = (__bf16)(acc[rg][1][i] * inv);
    }
  }
}

extern "C" void kernel_launch(void* const* d_in, const int* in_sizes, int n_in,
                              void* d_out, int out_size, void* d_ws, size_t ws_size,
                              hipStream_t stream) {
  const float* x      = (const float*)d_in[0];
  const float* W_attn = (const float*)d_in[1];
  const float* b_attn = (const float*)d_in[2];
  const float* W_proj = (const float*)d_in[3];
  const float* b_proj = (const float*)d_in[4];
  float* out = (float*)d_out;

  char* ws = (char*)d_ws;
  // region lifetimes: xb (A-input) dead after gemm_qkv; ob (flash output)
  // aliases xb. V is written ALREADY TRANSPOSED+time-permuted by gemm_qkv.
  __bf16* xb  = (__bf16*)(ws + 0);          // [8192,1024]
  __bf16* ob  = (__bf16*)(ws + 0);          // alias: [B,T,C] flash out
  __bf16* wab = (__bf16*)(ws + 16777216);   // [3072,1024]
  __bf16* wpb = (__bf16*)(ws + 23068672);   // [1024,1024]
  __bf16* qbf = (__bf16*)(ws + 25165824);   // [B,H,T,hd]
  __bf16* kbf = (__bf16*)(ws + 41943040);   // [B,H,T,hd]
  __bf16* vtb = (__bf16*)(ws + 58720256);   // [B,H,hd,T'] (transposed V)

  k_convert_x<<<8192, 256, 0, stream>>>(x, xb);
  k_transpose_w<<<dim3(32, 96), 256, 0, stream>>>(W_attn, wab, 3072);
  k_transpose_w<<<dim3(32, 32), 256, 0, stream>>>(W_proj, wpb, 1024);
  k_gemm_qkv<<<dim3(768), 256, 0, stream>>>(xb, wab, b_attn, qbf, kbf, vtb);
  k_flash<<<dim3(512), 256, 0, stream>>>(qbf, kbf, vtb, ob);
  k_gemm_proj<<<dim3(512), 256, 0, stream>>>(ob, wpb, b_proj, out);
}

// Round 8
// 238.174 us; speedup vs baseline: 1.0798x; 1.0798x over previous
//
#include <hip/hip_runtime.h>
#include <stdint.h>
#include <math.h>

typedef __attribute__((ext_vector_type(8))) __bf16 bf16x8;
typedef __attribute__((ext_vector_type(4))) __bf16 bf16x4;
typedef __attribute__((ext_vector_type(4))) float f32x4;
typedef __attribute__((ext_vector_type(16))) float f32x16;

#define MFMA16(A, B, C) __builtin_amdgcn_mfma_f32_16x16x32_bf16((A), (B), (C), 0, 0, 0)
#define MFMA32(A, B, C) __builtin_amdgcn_mfma_f32_32x32x16_bf16((A), (B), (C), 0, 0, 0)

#if defined(__has_builtin)
#if __has_builtin(__builtin_amdgcn_exp2f)
#define EXP2(x) __builtin_amdgcn_exp2f(x)
#else
#define EXP2(x) exp2f(x)
#endif
#else
#define EXP2(x) exp2f(x)
#endif

static constexpr int kT  = 2048;
static constexpr int kC  = 1024;
static constexpr int kHD = 64;
// q pre-scale: (1/sqrt(64)) * log2(e) so exp2(s') == exp(q.k/8)
#define QSCALE 0.1803368801111204f

__device__ __forceinline__ void g2l16(const void* g, void* l) {
  __builtin_amdgcn_global_load_lds(
      (const __attribute__((address_space(1))) uint32_t*)g,
      (__attribute__((address_space(3))) uint32_t*)l, 16, 0, 0);
}

// ---------------- x (f32) -> bf16, row-major [M, C] ----------------
__global__ __launch_bounds__(256) void k_convert_x(const float* __restrict__ x,
                                                   __bf16* __restrict__ xb) {
  int i = (blockIdx.x * 256 + threadIdx.x) * 4;
  f32x4 v = *(const f32x4*)(x + i);
  bf16x4 o;
  o[0] = (__bf16)v[0]; o[1] = (__bf16)v[1]; o[2] = (__bf16)v[2]; o[3] = (__bf16)v[3];
  *(bf16x4*)(xb + i) = o;
}

// ---- W [K=1024, N] f32 -> W^T [N, 1024] bf16 (B^T form for GEMM) ----
__global__ __launch_bounds__(256) void k_transpose_w(const float* __restrict__ src,
                                                     __bf16* __restrict__ dst, int N) {
  __shared__ float t[32][33];
  int k0 = blockIdx.x * 32, n0 = blockIdx.y * 32;
  int c = threadIdx.x & 31, r = threadIdx.x >> 5;
#pragma unroll
  for (int i = 0; i < 4; ++i)
    t[r + i * 8][c] = src[(size_t)(k0 + r + i * 8) * N + n0 + c];
  __syncthreads();
#pragma unroll
  for (int i = 0; i < 4; ++i)
    dst[(size_t)(n0 + r + i * 8) * 1024 + k0 + c] = (__bf16)t[c][r + i * 8];
}

// ---------------- GEMM: C[m,n] = sum_k A[m,k]*Bw[n,k] (+bias) ----------------
// r6-PROVEN geometry (76 us QKV): BM=BN=128, BK=32, 256 thr (4 waves 2Mx2N),
// ring-3 LDS 48 KiB -> 3 blocks/CU; counted vmcnt(4); one barrier/iter;
// granule-XOR swizzle (PMC-verified 0 conflicts).
// r8 change (semantics-preserving): K-loop unrolled by the ring period (3) so
// buffer indices are COMPILE-TIME -> ds_read/stage use constant LDS bases +
// immediate offsets; ring-index selects removed. Wait/stage sequence verified
// identical to r6: 30 uniform iters (stage j+2, vmcnt(4), barrier), then
// j=30 (no stage, vmcnt(0), barrier), j=31 (no stage, no wait).
// MODE 0: QKV -> q (scaled), k [B,H,T,hd]; v TRANSPOSED [bh][d][t'] with t'
// bits 2<->3 swapped in 16-groups (flash PV identity). MODE 1: proj f32+bias.
static constexpr int GK = 1024;
static constexpr int GNT = GK / 32;   // 32 K-tiles

template <int MODE>
__global__ __launch_bounds__(256, 3) void k_gemm(const __bf16* __restrict__ A,
                                                 const __bf16* __restrict__ Bw,
                                                 const float* __restrict__ bias,
                                                 __bf16* __restrict__ qo,
                                                 __bf16* __restrict__ ko,
                                                 __bf16* __restrict__ vo,
                                                 float* __restrict__ out) {
  __shared__ __bf16 As[3][128 * 32];   // 3 x 8 KiB
  __shared__ __bf16 Bs[3][128 * 32];   // 3 x 8 KiB

  const int tid = threadIdx.x;
  const int wave = tid >> 6, lane = tid & 63;
  const int lo = lane & 15, hi = lane >> 4;
  const int wr = wave & 1, wc = wave >> 1;

  constexpr int NBN = (MODE == 0) ? 24 : 8;
  const int nwg = (int)gridDim.x;
  const int id = (int)blockIdx.x;
  const int wg = (id & 7) * (nwg >> 3) + (id >> 3);
  const int bm = wg / NBN, bn = wg % NBN;
  const int m0 = bm * 128, n0 = bn * 128;

  const int rG0 = tid >> 2, gG0 = (tid & 3) ^ ((rG0 >> 1) & 3);
  const int rG1 = (tid + 256) >> 2, gG1 = ((tid + 256) & 3) ^ ((rG1 >> 1) & 3);
  const __bf16* gaA0 = A + (size_t)(m0 + rG0) * GK + gG0 * 8;
  const __bf16* gaA1 = A + (size_t)(m0 + rG1) * GK + gG1 * 8;
  const __bf16* gbB0 = Bw + (size_t)(n0 + rG0) * GK + gG0 * 8;
  const __bf16* gbB1 = Bw + (size_t)(n0 + rG1) * GK + gG1 * 8;

  const int fsw = (hi ^ ((lo >> 1) & 3)) * 8;
  const int offA = (wr * 64 + lo) * 32 + fsw;
  const int offB = (wc * 64 + lo) * 32 + fsw;

  f32x4 acc[4][4] = {};

#define GSTAGE(jt, bufi)                                  \
  {                                                       \
    g2l16(gaA0 + (jt) * 32, &As[(bufi)][tid * 8]);        \
    g2l16(gaA1 + (jt) * 32, &As[(bufi)][2048 + tid * 8]); \
    g2l16(gbB0 + (jt) * 32, &Bs[(bufi)][tid * 8]);        \
    g2l16(gbB1 + (jt) * 32, &Bs[(bufi)][2048 + tid * 8]); \
  }

  // one iteration body: read buf RB (tile JT), stage tile JT+2 into buf RS.
#define GMFMA(RB)                                                            \
  {                                                                          \
    bf16x8 af[4], bfr[4];                                                    \
    _Pragma("unroll")                                                        \
    for (int m = 0; m < 4; ++m)                                              \
      af[m] = *(const bf16x8*)&As[RB][offA + m * 512];                       \
    _Pragma("unroll")                                                        \
    for (int n = 0; n < 4; ++n)                                              \
      bfr[n] = *(const bf16x8*)&Bs[RB][offB + n * 512];                      \
    __builtin_amdgcn_s_setprio(1);                                           \
    _Pragma("unroll")                                                        \
    for (int m = 0; m < 4; ++m)                                              \
      _Pragma("unroll")                                                      \
      for (int n = 0; n < 4; ++n)                                            \
        acc[m][n] = MFMA16(af[m], bfr[n], acc[m][n]);                        \
    __builtin_amdgcn_s_setprio(0);                                           \
  }

#define GITER(RB, RS, JT)                          \
  {                                                \
    GSTAGE((JT) + 2, RS);                          \
    GMFMA(RB);                                     \
    asm volatile("s_waitcnt vmcnt(4)" ::: "memory"); \
    __builtin_amdgcn_s_barrier();                  \
    __builtin_amdgcn_sched_barrier(0);             \
  }

  // prologue: tiles 0,1 in flight; drain tile 0 (vmcnt 4), publish.
  GSTAGE(0, 0);
  GSTAGE(1, 1);
  asm volatile("s_waitcnt vmcnt(4)" ::: "memory");
  __builtin_amdgcn_s_barrier();
  __builtin_amdgcn_sched_barrier(0);

#pragma unroll 1
  for (int j = 0; j < GNT - 2; j += 3) {   // j = 0,3,...,27 -> iters 0..29
    GITER(0, 2, j);
    GITER(1, 0, j + 1);
    GITER(2, 1, j + 2);
  }
  // iter 30: read buf 0, no stage; drain tile 31; publish.
  GMFMA(0);
  asm volatile("s_waitcnt vmcnt(0)" ::: "memory");
  __builtin_amdgcn_s_barrier();
  __builtin_amdgcn_sched_barrier(0);
  // iter 31: read buf 1, no stage, no wait.
  GMFMA(1);

#undef GITER
#undef GMFMA
#undef GSTAGE

  if (MODE == 0) {
#pragma unroll
    for (int nj = 0; nj < 4; ++nj) {
      int gn = n0 + wc * 64 + nj * 16 + lo;
      float bv = bias[gn];
      int which = gn >> 10;          // 0=q 1=k 2=v (uniform per block: 128|1024)
      int c = gn & 1023;
      int hh = c >> 6, d = c & 63;
#pragma unroll
      for (int mi = 0; mi < 4; ++mi) {
        int gm = m0 + wr * 64 + mi * 16 + hi * 4;
        int bb = gm >> 11, t0 = gm & 2047;
        if (which == 2) {
          // V stored transposed [bh][d][t'] with t' = t bits 2<->3 swapped
          int t0p = t0 ^ ((((t0 >> 2) ^ (t0 >> 3)) & 1) * 12);
          bf16x4 vv;
#pragma unroll
          for (int r = 0; r < 4; ++r) vv[r] = (__bf16)(acc[mi][nj][r] + bv);
          *(bf16x4*)(vo + ((size_t)(bb * 16 + hh) * 64 + d) * 2048 + t0p) = vv;
        } else {
#pragma unroll
          for (int r = 0; r < 4; ++r) {
            float val = acc[mi][nj][r] + bv;
            size_t idx = (((size_t)(bb * 16 + hh)) * 2048 + (t0 + r)) * 64 + d;
            if (which == 0)
              qo[idx] = (__bf16)(val * QSCALE);
            else
              ko[idx] = (__bf16)val;
          }
        }
      }
    }
  } else {
#pragma unroll
    for (int nj = 0; nj < 4; ++nj) {
      int gn = n0 + wc * 64 + nj * 16 + lo;
      float bv = bias[gn];
#pragma unroll
      for (int mi = 0; mi < 4; ++mi) {
        int gm = m0 + wr * 64 + mi * 16 + hi * 4;
#pragma unroll
        for (int r = 0; r < 4; ++r)
          out[(size_t)(gm + r) * 1024 + gn] = acc[mi][nj][r] + bv;
      }
    }
  }
}

// ---------------- Flash attention (causal, no-max softmax) ----------------
// (r6-verified structure + r7 tail remap.) 32x32x16 swapped QK^T; lane-local
// linear P via V time-permutation; C-layout-aware normalizer redistribution.
// xs remap {0,1,2,3,7,6,5,4}: co-resident block pairs (id, id+256) get xs and
// 7-xs -> per-CU iteration sum constant at 50 (was 56..44).
__global__ __launch_bounds__(256, 2) void k_flash(const __bf16* __restrict__ qb,
                                                  const __bf16* __restrict__ kb,
                                                  const __bf16* __restrict__ vt,
                                                  __bf16* __restrict__ ob) {
  __shared__ __bf16 Ks[2][64 * 64];
  __shared__ __bf16 Vs[2][64 * 64];

  const int id = (int)blockIdx.x;
  const int xcd = id & 7, jj = id >> 3;
  const int bh = (jj & 7) * 8 + xcd;   // head-group pinned to one XCD
  const int xsi = jj >> 3;             // raw strip pair id, 0..7
  const int xs = (xsi < 4) ? xsi : 11 - xsi;   // tail-flattening remap
  const int b = bh >> 4, h = bh & 15;
  const int tid = threadIdx.x, wave = tid >> 6, lane = tid & 63;
  const int l31 = lane & 31, hi32 = lane >> 5;
  const int gx = l31 & 7;              // row part of granule swizzle

  // rg 0 = high strip (always active), rg 1 = low strip (active it<=2xs+1)
  const int qrow[2] = { (15 - xs) * 128 + wave * 32, xs * 128 + wave * 32 };

  // Q as B-frag: qf[rg][ks] = Q[qrow+l31][ks*16 + hi32*8 + e]
  bf16x8 qf[2][4];
#pragma unroll
  for (int rg = 0; rg < 2; ++rg) {
    const __bf16* Qp = qb + ((size_t)bh * kT + qrow[rg] + l31) * kHD + hi32 * 8;
#pragma unroll
    for (int ks = 0; ks < 4; ++ks)
      qf[rg][ks] = *(const bf16x8*)(Qp + ks * 16);
  }

  f32x16 acc[2][2] = {};      // [rg][db]: O[q=crow(reg,hi32)][d=db*32+l31]
  float srow[2] = {0.0f, 0.0f};

  const __bf16* Kbase = kb + (size_t)bh * kT * kHD;
  const __bf16* Vbase = vt + (size_t)bh * kHD * kT;

  int srcK[2], srcV[2];
#pragma unroll
  for (int p = 0; p < 2; ++p) {
    int g = wave * 64 + lane + p * 256;
    int r = g >> 3, c = g & 7;
    int cs = c ^ (r & 7);
    srcK[p] = r * kHD + cs * 8;   // + kt*64 per iteration
    srcV[p] = r * kT + cs * 8;    // + kt per iteration
  }

  const int nt = 32 - 2 * xs;

#pragma unroll
  for (int p = 0; p < 2; ++p) {
    g2l16(Kbase + srcK[p], &Ks[0][wave * 512 + p * 2048]);
    g2l16(Vbase + srcV[p], &Vs[0][wave * 512 + p * 2048]);
  }

  for (int it = 0; it < nt; ++it) {
    const int kt = it * 64;
    const int pb = it & 1;
    const bool both = (it <= 2 * xs + 1);

    __syncthreads();   // drains tile-it loads; all waves done with buf 1-pb

    if (it + 1 < nt) {
      const int kn = kt + 64;
#pragma unroll
      for (int p = 0; p < 2; ++p) {
        g2l16(Kbase + kn * kHD + srcK[p], &Ks[1 - pb][wave * 512 + p * 2048]);
        g2l16(Vbase + kn + srcV[p],       &Vs[1 - pb][wave * 512 + p * 2048]);
      }
    }

    const __bf16* Kt = &Ks[pb][0];
    const __bf16* Vt = &Vs[pb][0];

    bf16x8 pa[2][4];   // P A-frags per rg, per 16-key group

#pragma unroll
    for (int kb2 = 0; kb2 < 2; ++kb2) {
      bf16x8 ka[4];
#pragma unroll
      for (int ks = 0; ks < 4; ++ks)
        ka[ks] = *(const bf16x8*)&Kt[(kb2 * 32 + l31) * 64 +
                                     (((ks * 2 + hi32) ^ gx) * 8)];
#pragma unroll
      for (int rg = 0; rg < 2; ++rg) {
        if (rg == 1 && !both) break;
        // S^T[key][q]: lane q=l31; reg i -> key kt+kb2*32+(i&3)+8*(i>>2)+4*hi32
        f32x16 s = {};
        __builtin_amdgcn_s_setprio(1);
#pragma unroll
        for (int ks = 0; ks < 4; ++ks) s = MFMA32(ka[ks], qf[rg][ks], s);
        __builtin_amdgcn_s_setprio(0);
        const int qg = qrow[rg] + l31;
        const int kbs = kt + kb2 * 32 + 4 * hi32;
        if (kt + kb2 * 32 + 31 > qrow[rg]) {
#pragma unroll
          for (int i = 0; i < 16; ++i)
            if (kbs + (i & 3) + 8 * (i >> 2) > qg) s[i] = -INFINITY;
        }
#pragma unroll
        for (int i = 0; i < 16; ++i) s[i] = EXP2(s[i]);
        float sm = 0.0f;
#pragma unroll
        for (int i = 0; i < 16; ++i) sm += s[i];
        srow[rg] += sm;
        // P -> A-frag: LANE-LOCAL LINEAR pack (V time-permutation absorbs
        // the C-layout interleave): pa[kb2*2+a][e] = s[8a+e].
#pragma unroll
        for (int a = 0; a < 2; ++a) {
          bf16x8 p;
#pragma unroll
          for (int e = 0; e < 8; ++e) p[e] = (__bf16)s[8 * a + e];
          pa[rg][kb2 * 2 + a] = p;
        }
      }
    }

    // ---- O += P V: A=pa (P[32q x 16key]), B = V^T rows (V[key'][d]) ----
    __builtin_amdgcn_s_setprio(1);
#pragma unroll
    for (int db = 0; db < 2; ++db) {
#pragma unroll
      for (int ks = 0; ks < 4; ++ks) {
        bf16x8 vb = *(const bf16x8*)&Vt[(db * 32 + l31) * 64 +
                                        (((ks * 2 + hi32) ^ gx) * 8)];
        acc[0][db] = MFMA32(pa[0][ks], vb, acc[0][db]);
        if (both) acc[1][db] = MFMA32(pa[1][ks], vb, acc[1][db]);
      }
    }
    __builtin_amdgcn_s_setprio(0);
  }

  // epilogue: full row-sum for q=l31 via partner-half add; redistribute the
  // reciprocal to the lanes that STORE row q (C-layout row ownership).
#pragma unroll
  for (int rg = 0; rg < 2; ++rg) {
    float tot = srow[rg] + __shfl_xor(srow[rg], 32, 64);
    float invt = 1.0f / tot;       // valid for q = l31 (both hi32 halves)
    __bf16* Op = ob + ((size_t)b * kT + qrow[rg]) * kC + h * kHD;
#pragma unroll
    for (int i = 0; i < 16; ++i) {
      int q = (i & 3) + 8 * (i >> 2) + 4 * hi32;   // row this reg stores
      float inv = __shfl(invt, q, 64);             // row q's sum lives in lane q
      Op[(size_t)q * kC + l31]      = (__bf16)(acc[rg][0][i] * inv);
      Op[(size_t)q * kC + 32 + l31] = (__bf16)(acc[rg][1][i] * inv);
    }
  }
}

extern "C" void kernel_launch(void* const* d_in, const int* in_sizes, int n_in,
                              void* d_out, int out_size, void* d_ws, size_t ws_size,
                              hipStream_t stream) {
  const float* x      = (const float*)d_in[0];
  const float* W_attn = (const float*)d_in[1];
  const float* b_attn = (const float*)d_in[2];
  const float* W_proj = (const float*)d_in[3];
  const float* b_proj = (const float*)d_in[4];
  float* out = (float*)d_out;

  char* ws = (char*)d_ws;
  // region lifetimes: xb (A-input) dead after gemm<0>; ob (flash output)
  // aliases xb. V is written ALREADY TRANSPOSED+time-permuted by gemm<0>.
  __bf16* xb  = (__bf16*)(ws + 0);          // [8192,1024]
  __bf16* ob  = (__bf16*)(ws + 0);          // alias: [B,T,C] flash out
  __bf16* wab = (__bf16*)(ws + 16777216);   // [3072,1024]
  __bf16* wpb = (__bf16*)(ws + 23068672);   // [1024,1024]
  __bf16* qbf = (__bf16*)(ws + 25165824);   // [B,H,T,hd]
  __bf16* kbf = (__bf16*)(ws + 41943040);   // [B,H,T,hd]
  __bf16* vtb = (__bf16*)(ws + 58720256);   // [B,H,hd,T'] (transposed V)

  k_convert_x<<<8192, 256, 0, stream>>>(x, xb);
  k_transpose_w<<<dim3(32, 96), 256, 0, stream>>>(W_attn, wab, 3072);
  k_transpose_w<<<dim3(32, 32), 256, 0, stream>>>(W_proj, wpb, 1024);
  k_gemm<0><<<dim3(1536), 256, 0, stream>>>(xb, wab, b_attn, qbf, kbf, vtb, nullptr);
  k_flash<<<dim3(512), 256, 0, stream>>>(qbf, kbf, vtb, ob);
  k_gemm<1><<<dim3(512), 256, 0, stream>>>(ob, wpb, b_proj, nullptr, nullptr, nullptr, out);
}

// Round 9
// 237.716 us; speedup vs baseline: 1.0818x; 1.0019x over previous
//
#include <hip/hip_runtime.h>
#include <stdint.h>
#include <math.h>

typedef __attribute__((ext_vector_type(8))) __bf16 bf16x8;
typedef __attribute__((ext_vector_type(4))) __bf16 bf16x4;
typedef __attribute__((ext_vector_type(4))) float f32x4;
typedef __attribute__((ext_vector_type(16))) float f32x16;

#define MFMA16(A, B, C) __builtin_amdgcn_mfma_f32_16x16x32_bf16((A), (B), (C), 0, 0, 0)
#define MFMA32(A, B, C) __builtin_amdgcn_mfma_f32_32x32x16_bf16((A), (B), (C), 0, 0, 0)

#if defined(__has_builtin)
#if __has_builtin(__builtin_amdgcn_exp2f)
#define EXP2(x) __builtin_amdgcn_exp2f(x)
#else
#define EXP2(x) exp2f(x)
#endif
#else
#define EXP2(x) exp2f(x)
#endif

static constexpr int kT  = 2048;
static constexpr int kC  = 1024;
static constexpr int kHD = 64;
// q pre-scale: (1/sqrt(64)) * log2(e) so exp2(s') == exp(q.k/8)
#define QSCALE 0.1803368801111204f

__device__ __forceinline__ void g2l16(const void* g, void* l) {
  __builtin_amdgcn_global_load_lds(
      (const __attribute__((address_space(1))) uint32_t*)g,
      (__attribute__((address_space(3))) uint32_t*)l, 16, 0, 0);
}

// -------- fused prep: x f32->bf16 | W_attn^T | W_proj^T (one launch) --------
// blocks [0,8192): convert; [8192,11264): W_attn tile; [11264,12288): W_proj.
// Branch is block-uniform; __shared__ only used in transpose branches.
__global__ __launch_bounds__(256) void k_prep(const float* __restrict__ x,
                                              __bf16* __restrict__ xb,
                                              const float* __restrict__ Wa,
                                              __bf16* __restrict__ wab,
                                              const float* __restrict__ Wp,
                                              __bf16* __restrict__ wpb) {
  const int bid = (int)blockIdx.x;
  const int tid = threadIdx.x;
  if (bid < 8192) {
    int i = (bid * 256 + tid) * 4;
    f32x4 v = *(const f32x4*)(x + i);
    bf16x4 o;
    o[0] = (__bf16)v[0]; o[1] = (__bf16)v[1]; o[2] = (__bf16)v[2]; o[3] = (__bf16)v[3];
    *(bf16x4*)(xb + i) = o;
    return;
  }
  __shared__ float t[32][33];
  int tb = bid - 8192;
  const float* src; __bf16* dst; int N;
  if (tb < 3072) { src = Wa; dst = wab; N = 3072; }
  else           { tb -= 3072; src = Wp; dst = wpb; N = 1024; }
  const int k0 = (tb & 31) * 32, n0 = (tb >> 5) * 32;
  const int c = tid & 31, r = tid >> 5;
#pragma unroll
  for (int i = 0; i < 4; ++i)
    t[r + i * 8][c] = src[(size_t)(k0 + r + i * 8) * N + n0 + c];
  __syncthreads();
#pragma unroll
  for (int i = 0; i < 4; ++i)
    dst[(size_t)(n0 + r + i * 8) * 1024 + k0 + c] = (__bf16)t[c][r + i * 8];
}

// ---------------- GEMM: C[m,n] = sum_k A[m,k]*Bw[n,k] (+bias) ----------------
// r8-PROVEN: BM=BN=128, BK=32, 4 waves, ring-3 48 KiB -> 3 blocks/CU,
// counted vmcnt(4), one raw barrier/iter, granule-XOR swizzle (0 conflicts),
// ring unrolled by 3 (compile-time buffer indices).
// MODE 0: QKV -> q (scaled), k [B,H,T,hd]; v TRANSPOSED [bh][d][t'] with t'
// bits 2<->3 swapped in 16-groups (flash PV identity). MODE 1: proj f32+bias.
static constexpr int GK = 1024;
static constexpr int GNT = GK / 32;   // 32 K-tiles

template <int MODE>
__global__ __launch_bounds__(256, 3) void k_gemm(const __bf16* __restrict__ A,
                                                 const __bf16* __restrict__ Bw,
                                                 const float* __restrict__ bias,
                                                 __bf16* __restrict__ qo,
                                                 __bf16* __restrict__ ko,
                                                 __bf16* __restrict__ vo,
                                                 float* __restrict__ out) {
  __shared__ __bf16 As[3][128 * 32];   // 3 x 8 KiB
  __shared__ __bf16 Bs[3][128 * 32];   // 3 x 8 KiB

  const int tid = threadIdx.x;
  const int wave = tid >> 6, lane = tid & 63;
  const int lo = lane & 15, hi = lane >> 4;
  const int wr = wave & 1, wc = wave >> 1;

  constexpr int NBN = (MODE == 0) ? 24 : 8;
  const int nwg = (int)gridDim.x;
  const int id = (int)blockIdx.x;
  const int wg = (id & 7) * (nwg >> 3) + (id >> 3);
  const int bm = wg / NBN, bn = wg % NBN;
  const int m0 = bm * 128, n0 = bn * 128;

  const int rG0 = tid >> 2, gG0 = (tid & 3) ^ ((rG0 >> 1) & 3);
  const int rG1 = (tid + 256) >> 2, gG1 = ((tid + 256) & 3) ^ ((rG1 >> 1) & 3);
  const __bf16* gaA0 = A + (size_t)(m0 + rG0) * GK + gG0 * 8;
  const __bf16* gaA1 = A + (size_t)(m0 + rG1) * GK + gG1 * 8;
  const __bf16* gbB0 = Bw + (size_t)(n0 + rG0) * GK + gG0 * 8;
  const __bf16* gbB1 = Bw + (size_t)(n0 + rG1) * GK + gG1 * 8;

  const int fsw = (hi ^ ((lo >> 1) & 3)) * 8;
  const int offA = (wr * 64 + lo) * 32 + fsw;
  const int offB = (wc * 64 + lo) * 32 + fsw;

  f32x4 acc[4][4] = {};

#define GSTAGE(jt, bufi)                                  \
  {                                                       \
    g2l16(gaA0 + (jt) * 32, &As[(bufi)][tid * 8]);        \
    g2l16(gaA1 + (jt) * 32, &As[(bufi)][2048 + tid * 8]); \
    g2l16(gbB0 + (jt) * 32, &Bs[(bufi)][tid * 8]);        \
    g2l16(gbB1 + (jt) * 32, &Bs[(bufi)][2048 + tid * 8]); \
  }

#define GMFMA(RB)                                                            \
  {                                                                          \
    bf16x8 af[4], bfr[4];                                                    \
    _Pragma("unroll")                                                        \
    for (int m = 0; m < 4; ++m)                                              \
      af[m] = *(const bf16x8*)&As[RB][offA + m * 512];                       \
    _Pragma("unroll")                                                        \
    for (int n = 0; n < 4; ++n)                                              \
      bfr[n] = *(const bf16x8*)&Bs[RB][offB + n * 512];                      \
    __builtin_amdgcn_s_setprio(1);                                           \
    _Pragma("unroll")                                                        \
    for (int m = 0; m < 4; ++m)                                              \
      _Pragma("unroll")                                                      \
      for (int n = 0; n < 4; ++n)                                            \
        acc[m][n] = MFMA16(af[m], bfr[n], acc[m][n]);                        \
    __builtin_amdgcn_s_setprio(0);                                           \
  }

#define GITER(RB, RS, JT)                            \
  {                                                  \
    GSTAGE((JT) + 2, RS);                            \
    GMFMA(RB);                                       \
    asm volatile("s_waitcnt vmcnt(4)" ::: "memory"); \
    __builtin_amdgcn_s_barrier();                    \
    __builtin_amdgcn_sched_barrier(0);               \
  }

  GSTAGE(0, 0);
  GSTAGE(1, 1);
  asm volatile("s_waitcnt vmcnt(4)" ::: "memory");
  __builtin_amdgcn_s_barrier();
  __builtin_amdgcn_sched_barrier(0);

#pragma unroll 1
  for (int j = 0; j < GNT - 2; j += 3) {   // j = 0,3,...,27 -> iters 0..29
    GITER(0, 2, j);
    GITER(1, 0, j + 1);
    GITER(2, 1, j + 2);
  }
  GMFMA(0);
  asm volatile("s_waitcnt vmcnt(0)" ::: "memory");
  __builtin_amdgcn_s_barrier();
  __builtin_amdgcn_sched_barrier(0);
  GMFMA(1);

#undef GITER
#undef GMFMA
#undef GSTAGE

  if (MODE == 0) {
#pragma unroll
    for (int nj = 0; nj < 4; ++nj) {
      int gn = n0 + wc * 64 + nj * 16 + lo;
      float bv = bias[gn];
      int which = gn >> 10;          // 0=q 1=k 2=v (uniform per block: 128|1024)
      int c = gn & 1023;
      int hh = c >> 6, d = c & 63;
#pragma unroll
      for (int mi = 0; mi < 4; ++mi) {
        int gm = m0 + wr * 64 + mi * 16 + hi * 4;
        int bb = gm >> 11, t0 = gm & 2047;
        if (which == 2) {
          // V stored transposed [bh][d][t'] with t' = t bits 2<->3 swapped
          int t0p = t0 ^ ((((t0 >> 2) ^ (t0 >> 3)) & 1) * 12);
          bf16x4 vv;
#pragma unroll
          for (int r = 0; r < 4; ++r) vv[r] = (__bf16)(acc[mi][nj][r] + bv);
          *(bf16x4*)(vo + ((size_t)(bb * 16 + hh) * 64 + d) * 2048 + t0p) = vv;
        } else {
#pragma unroll
          for (int r = 0; r < 4; ++r) {
            float val = acc[mi][nj][r] + bv;
            size_t idx = (((size_t)(bb * 16 + hh)) * 2048 + (t0 + r)) * 64 + d;
            if (which == 0)
              qo[idx] = (__bf16)(val * QSCALE);
            else
              ko[idx] = (__bf16)val;
          }
        }
      }
    }
  } else {
#pragma unroll
    for (int nj = 0; nj < 4; ++nj) {
      int gn = n0 + wc * 64 + nj * 16 + lo;
      float bv = bias[gn];
#pragma unroll
      for (int mi = 0; mi < 4; ++mi) {
        int gm = m0 + wr * 64 + mi * 16 + hi * 4;
#pragma unroll
        for (int r = 0; r < 4; ++r)
          out[(size_t)(gm + r) * 1024 + gn] = acc[mi][nj][r] + bv;
      }
    }
  }
}

// ---------------- Flash attention (causal, no-max softmax) ----------------
// r9: the r6/r8-PROVEN GEMM pipeline schedule ported to flash. Ring-3 K/V
// buffers (48 KiB), stage tile it+2 at TOP of iter it, counted vmcnt(4) +
// raw s_barrier + sched_barrier(0) at bottom -- prefetch loads stay in
// flight across barriers (never drained to 0 until the tail), replacing the
// __syncthreads() vmcnt(0)-drain that exposed HBM/L2 latency every tile.
// Race proof == GEMM's: restage target (it+2)%3 is the buffer read at iter
// it-1, whose reads finished before the end-of-(it-1) barrier; reads of buf
// it%3 are covered by end-of-(it-1) vmcnt(4) (tile it landed) + barrier.
// Prologue vmcnt(4) also drains the older one-time Q loads (queue order).
// Compute structure unchanged (r6-verified): 32x32x16 swapped QK^T,
// lane-local linear P via V time-permutation, C-layout-aware normalizer
// redistribution; r7 xs remap for constant per-CU work.
__global__ __launch_bounds__(256, 2) void k_flash(const __bf16* __restrict__ qb,
                                                  const __bf16* __restrict__ kb,
                                                  const __bf16* __restrict__ vt,
                                                  __bf16* __restrict__ ob) {
  __shared__ __bf16 Ks[3][64 * 64];
  __shared__ __bf16 Vs[3][64 * 64];

  const int id = (int)blockIdx.x;
  const int xcd = id & 7, jj = id >> 3;
  const int bh = (jj & 7) * 8 + xcd;   // head-group pinned to one XCD
  const int xsi = jj >> 3;             // raw strip pair id, 0..7
  const int xs = (xsi < 4) ? xsi : 11 - xsi;   // tail-flattening remap
  const int b = bh >> 4, h = bh & 15;
  const int tid = threadIdx.x, wave = tid >> 6, lane = tid & 63;
  const int l31 = lane & 31, hi32 = lane >> 5;
  const int gx = l31 & 7;              // row part of granule swizzle

  // rg 0 = high strip (always active), rg 1 = low strip (active it<=2xs+1)
  const int qrow[2] = { (15 - xs) * 128 + wave * 32, xs * 128 + wave * 32 };

  // Q as B-frag: qf[rg][ks] = Q[qrow+l31][ks*16 + hi32*8 + e]
  bf16x8 qf[2][4];
#pragma unroll
  for (int rg = 0; rg < 2; ++rg) {
    const __bf16* Qp = qb + ((size_t)bh * kT + qrow[rg] + l31) * kHD + hi32 * 8;
#pragma unroll
    for (int ks = 0; ks < 4; ++ks)
      qf[rg][ks] = *(const bf16x8*)(Qp + ks * 16);
  }

  f32x16 acc[2][2] = {};      // [rg][db]: O[q=crow(reg,hi32)][d=db*32+l31]
  float srow[2] = {0.0f, 0.0f};

  const __bf16* Kbase = kb + (size_t)bh * kT * kHD;
  const __bf16* Vbase = vt + (size_t)bh * kHD * kT;

  int srcK[2], srcV[2];
#pragma unroll
  for (int p = 0; p < 2; ++p) {
    int g = wave * 64 + lane + p * 256;
    int r = g >> 3, c = g & 7;
    int cs = c ^ (r & 7);
    srcK[p] = r * kHD + cs * 8;   // + kt*64 per iteration
    srcV[p] = r * kT + cs * 8;    // + kt per iteration
  }

  const int nt = 32 - 2 * xs;    // >= 18, so prologue tiles 0,1 always exist

  // prologue: stage tiles 0,1 into bufs 0,1; drain tile 0 (vmcnt 4), publish.
#pragma unroll
  for (int p = 0; p < 2; ++p) {
    g2l16(Kbase + srcK[p], &Ks[0][wave * 512 + p * 2048]);
    g2l16(Vbase + srcV[p], &Vs[0][wave * 512 + p * 2048]);
  }
#pragma unroll
  for (int p = 0; p < 2; ++p) {
    g2l16(Kbase + 64 * kHD + srcK[p], &Ks[1][wave * 512 + p * 2048]);
    g2l16(Vbase + 64 + srcV[p],       &Vs[1][wave * 512 + p * 2048]);
  }
  asm volatile("s_waitcnt vmcnt(4)" ::: "memory");
  __builtin_amdgcn_s_barrier();
  __builtin_amdgcn_sched_barrier(0);

  int rb = 0, rs = 2;
  for (int it = 0; it < nt; ++it) {
    const int kt = it * 64;
    const bool both = (it <= 2 * xs + 1);

    if (it + 2 < nt) {
      const int kn = kt + 128;
#pragma unroll
      for (int p = 0; p < 2; ++p) {
        g2l16(Kbase + kn * kHD + srcK[p], &Ks[rs][wave * 512 + p * 2048]);
        g2l16(Vbase + kn + srcV[p],       &Vs[rs][wave * 512 + p * 2048]);
      }
    }

    const __bf16* Kt = &Ks[rb][0];
    const __bf16* Vt = &Vs[rb][0];

    bf16x8 pa[2][4];   // P A-frags per rg, per 16-key group

#pragma unroll
    for (int kb2 = 0; kb2 < 2; ++kb2) {
      bf16x8 ka[4];
#pragma unroll
      for (int ks = 0; ks < 4; ++ks)
        ka[ks] = *(const bf16x8*)&Kt[(kb2 * 32 + l31) * 64 +
                                     (((ks * 2 + hi32) ^ gx) * 8)];
#pragma unroll
      for (int rg = 0; rg < 2; ++rg) {
        if (rg == 1 && !both) break;
        // S^T[key][q]: lane q=l31; reg i -> key kt+kb2*32+(i&3)+8*(i>>2)+4*hi32
        f32x16 s = {};
        __builtin_amdgcn_s_setprio(1);
#pragma unroll
        for (int ks = 0; ks < 4; ++ks) s = MFMA32(ka[ks], qf[rg][ks], s);
        __builtin_amdgcn_s_setprio(0);
        const int qg = qrow[rg] + l31;
        const int kbs = kt + kb2 * 32 + 4 * hi32;
        if (kt + kb2 * 32 + 31 > qrow[rg]) {
#pragma unroll
          for (int i = 0; i < 16; ++i)
            if (kbs + (i & 3) + 8 * (i >> 2) > qg) s[i] = -INFINITY;
        }
#pragma unroll
        for (int i = 0; i < 16; ++i) s[i] = EXP2(s[i]);
        float sm = 0.0f;
#pragma unroll
        for (int i = 0; i < 16; ++i) sm += s[i];
        srow[rg] += sm;
        // P -> A-frag: LANE-LOCAL LINEAR pack (V time-permutation absorbs
        // the C-layout interleave): pa[kb2*2+a][e] = s[8a+e].
#pragma unroll
        for (int a = 0; a < 2; ++a) {
          bf16x8 p;
#pragma unroll
          for (int e = 0; e < 8; ++e) p[e] = (__bf16)s[8 * a + e];
          pa[rg][kb2 * 2 + a] = p;
        }
      }
    }

    // ---- O += P V: A=pa (P[32q x 16key]), B = V^T rows (V[key'][d]) ----
    __builtin_amdgcn_s_setprio(1);
#pragma unroll
    for (int db = 0; db < 2; ++db) {
#pragma unroll
      for (int ks = 0; ks < 4; ++ks) {
        bf16x8 vb = *(const bf16x8*)&Vt[(db * 32 + l31) * 64 +
                                        (((ks * 2 + hi32) ^ gx) * 8)];
        acc[0][db] = MFMA32(pa[0][ks], vb, acc[0][db]);
        if (both) acc[1][db] = MFMA32(pa[1][ks], vb, acc[1][db]);
      }
    }
    __builtin_amdgcn_s_setprio(0);

    // counted end-of-iter wait: tile it+1 landed; tile it+2 stays in flight
    if (it + 2 < nt) {
      asm volatile("s_waitcnt vmcnt(4)" ::: "memory");
    } else if (it + 2 == nt) {
      asm volatile("s_waitcnt vmcnt(0)" ::: "memory");
    }
    if (it + 1 < nt) {
      __builtin_amdgcn_s_barrier();
      __builtin_amdgcn_sched_barrier(0);
    }
    rb = (rb == 2) ? 0 : rb + 1;
    rs = (rs == 2) ? 0 : rs + 1;
  }

  // epilogue: full row-sum for q=l31 via partner-half add; redistribute the
  // reciprocal to the lanes that STORE row q (C-layout row ownership).
#pragma unroll
  for (int rg = 0; rg < 2; ++rg) {
    float tot = srow[rg] + __shfl_xor(srow[rg], 32, 64);
    float invt = 1.0f / tot;       // valid for q = l31 (both hi32 halves)
    __bf16* Op = ob + ((size_t)b * kT + qrow[rg]) * kC + h * kHD;
#pragma unroll
    for (int i = 0; i < 16; ++i) {
      int q = (i & 3) + 8 * (i >> 2) + 4 * hi32;   // row this reg stores
      float inv = __shfl(invt, q, 64);             // row q's sum lives in lane q
      Op[(size_t)q * kC + l31]      = (__bf16)(acc[rg][0][i] * inv);
      Op[(size_t)q * kC + 32 + l31] = (__bf16)(acc[rg][1][i] * inv);
    }
  }
}

extern "C" void kernel_launch(void* const* d_in, const int* in_sizes, int n_in,
                              void* d_out, int out_size, void* d_ws, size_t ws_size,
                              hipStream_t stream) {
  const float* x      = (const float*)d_in[0];
  const float* W_attn = (const float*)d_in[1];
  const float* b_attn = (const float*)d_in[2];
  const float* W_proj = (const float*)d_in[3];
  const float* b_proj = (const float*)d_in[4];
  float* out = (float*)d_out;

  char* ws = (char*)d_ws;
  // region lifetimes: xb (A-input) dead after gemm<0>; ob (flash output)
  // aliases xb. V is written ALREADY TRANSPOSED+time-permuted by gemm<0>.
  __bf16* xb  = (__bf16*)(ws + 0);          // [8192,1024]
  __bf16* ob  = (__bf16*)(ws + 0);          // alias: [B,T,C] flash out
  __bf16* wab = (__bf16*)(ws + 16777216);   // [3072,1024]
  __bf16* wpb = (__bf16*)(ws + 23068672);   // [1024,1024]
  __bf16* qbf = (__bf16*)(ws + 25165824);   // [B,H,T,hd]
  __bf16* kbf = (__bf16*)(ws + 41943040);   // [B,H,T,hd]
  __bf16* vtb = (__bf16*)(ws + 58720256);   // [B,H,hd,T'] (transposed V)

  k_prep<<<12288, 256, 0, stream>>>(x, xb, W_attn, wab, W_proj, wpb);
  k_gemm<0><<<dim3(1536), 256, 0, stream>>>(xb, wab, b_attn, qbf, kbf, vtb, nullptr);
  k_flash<<<dim3(512), 256, 0, stream>>>(qbf, kbf, vtb, ob);
  k_gemm<1><<<dim3(512), 256, 0, stream>>>(ob, wpb, b_proj, nullptr, nullptr, nullptr, out);
}